// Round 10
// baseline (234.787 us; speedup 1.0000x reference)
//
#include <hip/hip_runtime.h>
#include <hip/hip_bf16.h>

#define NTOK    32768
#define DIMD    1024
#define RNK     128
#define NEXP    7
#define FULLKEY 7
#define NTILEX  152     // tiles of 16 tokens, grid-stride

using f32x4 = __attribute__((ext_vector_type(4))) float;
using s16x8 = __attribute__((ext_vector_type(8))) short;

__device__ __forceinline__ unsigned short f2bf(float f) {
    unsigned u = __float_as_uint(f);
    u += 0x7fffu + ((u >> 16) & 1u);   // RNE; inputs have no NaN
    return (unsigned short)(u >> 16);
}

__device__ __forceinline__ unsigned lra_bits(const int* __restrict__ mask) {
    unsigned bits = 0u;
#pragma unroll
    for (int i = 0; i < NEXP; ++i) {
        int m = mask[i];
        m = m < 0 ? 0 : (m > 7 ? 7 : m);
        bits |= (1u << m);
    }
    return bits;
}

// ---- prep: weights -> fragment-linear bf16 buffers | bucket | inactive copy ----
// WdF: byte off = e*262144 + kc*8192 + nn*1024 + l*16  (kc=k/32 0..31, nn=rtile 0..7, l=lane)
//      holds Wd[e][r = nn*16 + (l&15)][k = kc*32 + (l>>4)*8 .. +8]
// WuF: byte off = e*262144 + dc*16384 + (ks*4+nn)*1024 + l*16  (dc=d/64, ks=rank/32, nn=dtile)
//      holds Wu[e][d = dc*64 + nn*16 + (l&15)][r = ks*32 + (l>>4)*8 .. +8]
__global__ void prep_kernel(const float* __restrict__ x, const int* __restrict__ ridx,
                            const int* __restrict__ mask,
                            const float* __restrict__ Wd, const float* __restrict__ Wu,
                            char* __restrict__ WdF, char* __restrict__ WuF,
                            int* __restrict__ counts, int* __restrict__ bucket,
                            float* __restrict__ out) {
    const int b = blockIdx.x;
    const int tid = threadIdx.x;
    if (b < 896) {
        const int id8 = b * 256 + tid;         // one 16B frag-slot (8 elems) per thread
        const int NE8 = 114688;                // 917504/8
        const float* src;
        char* dst;
        if (id8 < NE8) {
            const int e = id8 >> 14, rem = id8 & 16383;
            const int kc = rem >> 9, nn = (rem >> 6) & 7, l = rem & 63;
            const int r = nn * 16 + (l & 15);
            const int k = kc * 32 + (l >> 4) * 8;
            src = Wd + ((size_t)(e * RNK + r)) * DIMD + k;
            dst = WdF + (size_t)id8 * 16;
        } else {
            const int id = id8 - NE8;
            const int e = id >> 14, rem = id & 16383;
            const int dc = rem >> 10, ksn = (rem >> 6) & 15, l = rem & 63;
            const int d = dc * 64 + (ksn & 3) * 16 + (l & 15);
            const int r = (ksn >> 2) * 32 + (l >> 4) * 8;
            src = Wu + ((size_t)(e * DIMD + d)) * RNK + r;
            dst = WuF + (size_t)id * 16;
        }
        const float4 v0 = *reinterpret_cast<const float4*>(src);
        const float4 v1 = *reinterpret_cast<const float4*>(src + 4);
        ushort4 o0, o1;
        o0.x = f2bf(v0.x); o0.y = f2bf(v0.y); o0.z = f2bf(v0.z); o0.w = f2bf(v0.w);
        o1.x = f2bf(v1.x); o1.y = f2bf(v1.y); o1.z = f2bf(v1.z); o1.w = f2bf(v1.w);
        *reinterpret_cast<ushort4*>(dst) = o0;
        *reinterpret_cast<ushort4*>(dst + 8) = o1;
    } else if (b < 1024) {
        // bucket: LDS-aggregated atomics (R5-verified)
        __shared__ int lcnt[8];
        __shared__ int lbase[8];
        if (tid < 8) lcnt[tid] = 0;
        __syncthreads();
        const int t = (b - 896) * 256 + tid;
        const unsigned bits = lra_bits(mask);
        const int k = ridx[t];
        const bool act = (k != FULLKEY) && ((bits >> k) & 1u);
        int pos = -1;
        if (act) pos = atomicAdd(&lcnt[k], 1);
        __syncthreads();
        if (tid < 8 && lcnt[tid] > 0) lbase[tid] = atomicAdd(&counts[tid], lcnt[tid]);
        __syncthreads();
        if (act) bucket[k * NTOK + lbase[k] + pos] = t;
    } else {
        unsigned bits = lra_bits(mask);
        for (int t = b - 1024; t < NTOK; t += 2048) {
            int k = ridx[t];
            bool act = (k != FULLKEY) && ((bits >> k) & 1u);
            if (!act) {
                const float4* src = reinterpret_cast<const float4*>(x + (size_t)t * DIMD);
                float4* dst = reinterpret_cast<float4*>(out + (size_t)t * DIMD);
                dst[tid] = src[tid];
            }
        }
    }
}

// ---- fused expert, 4x TLP (R8 structure, spill-free): block = 4 waves / 16 tokens.
// wave w: down partial over K-quarter -> LDS f32 [16][132] -> barrier ->
// each wave reduces to full-rank a2 frags -> wave w: up over its 4 dc-chunks. ----
__launch_bounds__(256)
__global__ void expert_kernel(const float* __restrict__ x,
                              const char* __restrict__ WdF,
                              const char* __restrict__ WuF,
                              const int* __restrict__ counts,
                              const int* __restrict__ bucket,
                              float* __restrict__ out) {
    const int e = blockIdx.y;
    const int n = counts[e];
    const int tid = threadIdx.x;
    const int w = tid >> 6, l = tid & 63, l15 = l & 15, lk = l >> 4;
    const int* bkt = bucket + e * NTOK;

    __shared__ __align__(16) float pbuf[4][16 * 132];   // 33 KB: per-wave down partials, pad 132

    const char* WdE = WdF + (size_t)e * 262144;
    const char* WuE = WuF + (size_t)e * 262144;
    const f32x4 zero = {0.f, 0.f, 0.f, 0.f};

    for (int tile = blockIdx.x; tile * 16 < n; tile += gridDim.x) {
        int idx = tile * 16 + l15;
        if (idx >= n) idx = n - 1;
        const int t = bkt[idx];
        int t4[4];
#pragma unroll
        for (int j = 0; j < 4; ++j) t4[j] = __shfl(t, lk * 4 + j);

        // ---------- down partial: K in [w*256, w*256+256) ----------
        const float* xr = x + (size_t)t * DIMD + w * 256;
        f32x4 accD[8];
#pragma unroll
        for (int i = 0; i < 8; ++i) accD[i] = zero;

#pragma unroll
        for (int kc = 0; kc < 8; ++kc) {
            const float* p = xr + kc * 32 + lk * 8;
            const f32x4 v0 = *reinterpret_cast<const f32x4*>(p);
            const f32x4 v1 = *reinterpret_cast<const f32x4*>(p + 4);
            s16x8 a;
#pragma unroll
            for (int j = 0; j < 4; ++j) {
                a[j]     = (short)f2bf(v0[j]);
                a[4 + j] = (short)f2bf(v1[j]);
            }
            const char* wp = WdE + (w * 8 + kc) * 8192 + l * 16;
            s16x8 bfr[8];
#pragma unroll
            for (int nn = 0; nn < 8; ++nn)
                bfr[nn] = *reinterpret_cast<const s16x8*>(wp + nn * 1024);
#pragma unroll
            for (int nn = 0; nn < 8; ++nn)
                accD[nn] = __builtin_amdgcn_mfma_f32_16x16x32_bf16(a, bfr[nn], accD[nn], 0, 0, 0);
        }

        // write partials: C layout (tok=lk*4+j, rank=nn*16+l15); stride 132 -> 2-way (free)
#pragma unroll
        for (int nn = 0; nn < 8; ++nn) {
#pragma unroll
            for (int j = 0; j < 4; ++j) {
                pbuf[w][(lk * 4 + j) * 132 + nn * 16 + l15] = accD[nn][j];
            }
        }
        __syncthreads();

        // ---------- reduce 4 partials -> a2 (tok=l15, ranks ks*32+lk*8..+8) ----------
        s16x8 a2[4];
#pragma unroll
        for (int ks = 0; ks < 4; ++ks) {
            f32x4 s0 = zero, s1 = zero;
#pragma unroll
            for (int pw = 0; pw < 4; ++pw) {
                const float* pb = &pbuf[pw][l15 * 132 + ks * 32 + lk * 8];
                s0 += *reinterpret_cast<const f32x4*>(pb);
                s1 += *reinterpret_cast<const f32x4*>(pb + 4);
            }
            s16x8 av;
#pragma unroll
            for (int j = 0; j < 4; ++j) {
                av[j]     = (short)f2bf(s0[j]);
                av[4 + j] = (short)f2bf(s1[j]);
            }
            a2[ks] = av;
        }

        // ---------- up: wave w owns dc = w*4 .. w*4+3 (256 dims); out = x + acc ----------
#pragma unroll
        for (int q = 0; q < 4; ++q) {
            const int dc = w * 4 + q;
            const char* wq = WuE + dc * 16384 + l * 16;
            f32x4 accU[4];
#pragma unroll
            for (int i = 0; i < 4; ++i) accU[i] = zero;
            // two half-batches of 8 frags to cap peak VGPR (~110)
#pragma unroll
            for (int hb = 0; hb < 2; ++hb) {
                s16x8 bfr[8];
#pragma unroll
                for (int i = 0; i < 8; ++i)
                    bfr[i] = *reinterpret_cast<const s16x8*>(wq + (hb * 8 + i) * 1024);
#pragma unroll
                for (int ks = 0; ks < 2; ++ks) {
#pragma unroll
                    for (int nn = 0; nn < 4; ++nn) {
                        accU[nn] = __builtin_amdgcn_mfma_f32_16x16x32_bf16(
                            a2[hb * 2 + ks], bfr[ks * 4 + nn], accU[nn], 0, 0, 0);
                    }
                }
            }
#pragma unroll
            for (int nn = 0; nn < 4; ++nn) {
#pragma unroll
                for (int j = 0; j < 4; ++j) {
                    const size_t off = (size_t)t4[j] * DIMD + dc * 64 + nn * 16 + l15;
                    out[off] = x[off] + accU[nn][j];
                }
            }
        }
        __syncthreads();   // pbuf readers done before next tile's writes
    }
}

extern "C" void kernel_launch(void* const* d_in, const int* in_sizes, int n_in,
                              void* d_out, int out_size, void* d_ws, size_t ws_size,
                              hipStream_t stream) {
    const float* x  = (const float*)d_in[0];
    const int* ridx = (const int*)d_in[1];
    const int* mask = (const int*)d_in[2];
    const float* Wd = (const float*)d_in[3];
    const float* Wu = (const float*)d_in[4];
    float* out = (float*)d_out;

    char* ws = (char*)d_ws;
    int* counts = (int*)ws;                 // 256 B
    int* bucket = (int*)(ws + 256);         // 917504 B
    char* WdF = ws + 917760;                // 1835008 B
    char* WuF = ws + 2752768;               // 1835008 B
    // total ~4.6 MB

    hipMemsetAsync(counts, 0, 8 * sizeof(int), stream);
    prep_kernel<<<dim3(3072), dim3(256), 0, stream>>>(x, ridx, mask, Wd, Wu, WdF, WuF, counts, bucket, out);
    expert_kernel<<<dim3(NTILEX, NEXP), dim3(256), 0, stream>>>(x, WdF, WuF, counts, bucket, out);
}

// Round 14
// 96.723 us; speedup vs baseline: 2.4274x; 2.4274x over previous
//
#include <hip/hip_runtime.h>
#include <hip/hip_bf16.h>

#define NTOK    32768
#define DIMD    1024
#define RNK     128
#define NEXP    7
#define FULLKEY 7

using f32x4 = __attribute__((ext_vector_type(4))) float;
using s16x8 = __attribute__((ext_vector_type(8))) short;

__device__ __forceinline__ unsigned short f2bf(float f) {
    unsigned u = __float_as_uint(f);
    u += 0x7fffu + ((u >> 16) & 1u);   // RNE; inputs have no NaN
    return (unsigned short)(u >> 16);
}

__device__ __forceinline__ unsigned lra_bits(const int* __restrict__ mask) {
    unsigned bits = 0u;
#pragma unroll
    for (int i = 0; i < NEXP; ++i) {
        int m = mask[i];
        m = m < 0 ? 0 : (m > 7 ? 7 : m);
        bits |= (1u << m);
    }
    return bits;
}

// ---- prep: weights -> fragment-linear bf16 buffers | bucket | inactive copy ----
// WdF: byte off = e*262144 + kc*8192 + nn*1024 + l*16  (kc=k/32 0..31, nn=rtile 0..7, l=lane)
//      holds Wd[e][r = nn*16 + (l&15)][k = kc*32 + (l>>4)*8 .. +8]
// WuF: byte off = e*262144 + dc*16384 + (ks*4+nn)*1024 + l*16  (dc=d/64, ks=rank/32, nn=dtile)
//      holds Wu[e][d = dc*64 + nn*16 + (l&15)][r = ks*32 + (l>>4)*8 .. +8]
__global__ void prep_kernel(const float* __restrict__ x, const int* __restrict__ ridx,
                            const int* __restrict__ mask,
                            const float* __restrict__ Wd, const float* __restrict__ Wu,
                            char* __restrict__ WdF, char* __restrict__ WuF,
                            int* __restrict__ counts, int* __restrict__ bucket,
                            float* __restrict__ out) {
    const int b = blockIdx.x;
    const int tid = threadIdx.x;
    if (b < 896) {
        const int id8 = b * 256 + tid;         // one 16B frag-slot (8 elems) per thread
        const int NE8 = 114688;                // 917504/8
        const float* src;
        char* dst;
        if (id8 < NE8) {
            const int e = id8 >> 14, rem = id8 & 16383;
            const int kc = rem >> 9, nn = (rem >> 6) & 7, l = rem & 63;
            const int r = nn * 16 + (l & 15);
            const int k = kc * 32 + (l >> 4) * 8;
            src = Wd + ((size_t)(e * RNK + r)) * DIMD + k;
            dst = WdF + (size_t)id8 * 16;
        } else {
            const int id = id8 - NE8;
            const int e = id >> 14, rem = id & 16383;
            const int dc = rem >> 10, ksn = (rem >> 6) & 15, l = rem & 63;
            const int d = dc * 64 + (ksn & 3) * 16 + (l & 15);
            const int r = (ksn >> 2) * 32 + (l >> 4) * 8;
            src = Wu + ((size_t)(e * DIMD + d)) * RNK + r;
            dst = WuF + (size_t)id * 16;
        }
        const float4 v0 = *reinterpret_cast<const float4*>(src);
        const float4 v1 = *reinterpret_cast<const float4*>(src + 4);
        ushort4 o0, o1;
        o0.x = f2bf(v0.x); o0.y = f2bf(v0.y); o0.z = f2bf(v0.z); o0.w = f2bf(v0.w);
        o1.x = f2bf(v1.x); o1.y = f2bf(v1.y); o1.z = f2bf(v1.z); o1.w = f2bf(v1.w);
        *reinterpret_cast<ushort4*>(dst) = o0;
        *reinterpret_cast<ushort4*>(dst + 8) = o1;
    } else if (b < 1024) {
        // bucket: LDS-aggregated atomics (R5-verified)
        __shared__ int lcnt[8];
        __shared__ int lbase[8];
        if (tid < 8) lcnt[tid] = 0;
        __syncthreads();
        const int t = (b - 896) * 256 + tid;
        const unsigned bits = lra_bits(mask);
        const int k = ridx[t];
        const bool act = (k != FULLKEY) && ((bits >> k) & 1u);
        int pos = -1;
        if (act) pos = atomicAdd(&lcnt[k], 1);
        __syncthreads();
        if (tid < 8 && lcnt[tid] > 0) lbase[tid] = atomicAdd(&counts[tid], lcnt[tid]);
        __syncthreads();
        if (act) bucket[k * NTOK + lbase[k] + pos] = t;
    } else {
        unsigned bits = lra_bits(mask);
        for (int t = b - 1024; t < NTOK; t += 2048) {
            int k = ridx[t];
            bool act = (k != FULLKEY) && ((bits >> k) & 1u);
            if (!act) {
                const float4* src = reinterpret_cast<const float4*>(x + (size_t)t * DIMD);
                float4* dst = reinterpret_cast<float4*>(out + (size_t)t * DIMD);
                dst[tid] = src[tid];
            }
        }
    }
}

// ---- fused expert, barrier-free (R7-verified): each wave owns 16 tokens end-to-end.
// B-frags read as wave-contiguous 1KB loads from fragment-linear L2-resident buffers.
// down accumulators transposed to up A-frags via per-wave private LDS (no sync).
// R14 delta vs R7: kc loop unroll 2 -> 4, dc loop unroll 2 (deeper MLP). ----
__launch_bounds__(256)
__global__ void expert_kernel(const float* __restrict__ x,
                              const char* __restrict__ WdF,
                              const char* __restrict__ WuF,
                              const int* __restrict__ counts,
                              const int* __restrict__ bucket,
                              float* __restrict__ out) {
    const int e = blockIdx.y;
    const int n = counts[e];
    const int tid = threadIdx.x;
    const int w = tid >> 6, l = tid & 63, l15 = l & 15, lk = l >> 4;
    const int* bkt = bucket + e * NTOK;

    __shared__ __align__(16) unsigned short tBuf[4][2048];   // 4KB per wave, private
    char* tb = reinterpret_cast<char*>(tBuf[w]);

    const char* WdE = WdF + (size_t)e * 262144;
    const char* WuE = WuF + (size_t)e * 262144;
    const f32x4 zero = {0.f, 0.f, 0.f, 0.f};

    for (int tile = blockIdx.x; tile * 64 < n; tile += gridDim.x) {
        int idx = tile * 64 + w * 16 + l15;
        if (idx >= n) idx = n - 1;
        const int t = bkt[idx];
        const float* xr = x + (size_t)t * DIMD;
        int t4[4];
#pragma unroll
        for (int j = 0; j < 4; ++j) t4[j] = __shfl(t, lk * 4 + j);

        // ---------- down: accD[8] = 16 tok x 128 rank ----------
        f32x4 accD[8];
#pragma unroll
        for (int i = 0; i < 8; ++i) accD[i] = zero;

#pragma unroll 4
        for (int kc = 0; kc < 32; ++kc) {
            const float* p = xr + kc * 32 + lk * 8;
            const f32x4 v0 = *reinterpret_cast<const f32x4*>(p);
            const f32x4 v1 = *reinterpret_cast<const f32x4*>(p + 4);
            s16x8 a;
#pragma unroll
            for (int j = 0; j < 4; ++j) {
                a[j]     = (short)f2bf(v0[j]);
                a[4 + j] = (short)f2bf(v1[j]);
            }
            const char* wp = WdE + kc * 8192 + l * 16;
            s16x8 bfr[8];
#pragma unroll
            for (int nn = 0; nn < 8; ++nn)
                bfr[nn] = *reinterpret_cast<const s16x8*>(wp + nn * 1024);
#pragma unroll
            for (int nn = 0; nn < 8; ++nn)
                accD[nn] = __builtin_amdgcn_mfma_f32_16x16x32_bf16(a, bfr[nn], accD[nn], 0, 0, 0);
        }

        // ---------- transpose accD (rank=l15, tok=lk*4+j) -> a2 (tok=l15) via private LDS ----------
#pragma unroll
        for (int nn = 0; nn < 8; ++nn) {
#pragma unroll
            for (int j = 0; j < 4; ++j) {
                const int row = lk * 4 + j;
                const int cb2 = (nn * 16 + l15) * 2;
                *reinterpret_cast<unsigned short*>(
                    tb + row * 256 + (cb2 ^ ((row & 7) << 4))) = f2bf(accD[nn][j]);
            }
        }
        s16x8 a2[4];
#pragma unroll
        for (int ks = 0; ks < 4; ++ks)
            a2[ks] = *reinterpret_cast<const s16x8*>(
                tb + l15 * 256 + ((ks * 64 + lk * 16) ^ ((l15 & 7) << 4)));

        // ---------- up: 16 chunks of 64 dims; epilogue out = x + acc ----------
#pragma unroll 2
        for (int dc = 0; dc < 16; ++dc) {
            const char* wq = WuE + dc * 16384 + l * 16;
            s16x8 bfr[16];
#pragma unroll
            for (int i = 0; i < 16; ++i)
                bfr[i] = *reinterpret_cast<const s16x8*>(wq + i * 1024);
            f32x4 accU[4];
#pragma unroll
            for (int i = 0; i < 4; ++i) accU[i] = zero;
#pragma unroll
            for (int ks = 0; ks < 4; ++ks) {
#pragma unroll
                for (int nn = 0; nn < 4; ++nn) {
                    accU[nn] = __builtin_amdgcn_mfma_f32_16x16x32_bf16(
                        a2[ks], bfr[ks * 4 + nn], accU[nn], 0, 0, 0);
                }
            }
#pragma unroll
            for (int nn = 0; nn < 4; ++nn) {
#pragma unroll
                for (int j = 0; j < 4; ++j) {
                    const size_t off = (size_t)t4[j] * DIMD + dc * 64 + nn * 16 + l15;
                    out[off] = x[off] + accU[nn][j];
                }
            }
        }
    }
}

extern "C" void kernel_launch(void* const* d_in, const int* in_sizes, int n_in,
                              void* d_out, int out_size, void* d_ws, size_t ws_size,
                              hipStream_t stream) {
    const float* x  = (const float*)d_in[0];
    const int* ridx = (const int*)d_in[1];
    const int* mask = (const int*)d_in[2];
    const float* Wd = (const float*)d_in[3];
    const float* Wu = (const float*)d_in[4];
    float* out = (float*)d_out;

    char* ws = (char*)d_ws;
    int* counts = (int*)ws;                 // 256 B
    int* bucket = (int*)(ws + 256);         // 917504 B
    char* WdF = ws + 917760;                // 1835008 B (7 x 32 x 8 x 64 x 16B)
    char* WuF = ws + 2752768;               // 1835008 B (7 x 16 x 16 x 64 x 16B)
    // total ~4.6 MB

    hipMemsetAsync(counts, 0, 8 * sizeof(int), stream);
    prep_kernel<<<dim3(3072), dim3(256), 0, stream>>>(x, ridx, mask, Wd, Wu, WdF, WuF, counts, bucket, out);
    expert_kernel<<<dim3(68, NEXP), dim3(256), 0, stream>>>(x, WdF, WuF, counts, bucket, out);
}